// Round 6
// baseline (141.907 us; speedup 1.0000x reference)
//
#include <hip/hip_runtime.h>
#include <math.h>

#define Dd 160
#define Hh 160
#define Ww 160
#define TW 32
#define TH 32
#define DCHUNK 16
#define NSLICE (DCHUNK + 4)   // 20
#define NT 320
#define NCH 5
#define PDIM 36               // rows 0..35; bank spread via 36-stride (4*cw mod 32)
#define SLICE (Hh * Ww)
#define NDC (Dd / DCHUNK)     // 10

__global__ void lncc_zero(float* out) { out[0] = 0.0f; }

// Barrier draining LDS ops only — global prefetch loads stay in flight across it.
__device__ __forceinline__ void bar_lgkm() {
    asm volatile("s_waitcnt lgkmcnt(0)" ::: "memory");
    __builtin_amdgcn_s_barrier();
    asm volatile("" ::: "memory");
}

__global__ __launch_bounds__(NT, 2)
void lncc_main(const float* __restrict__ M, const float* __restrict__ R,
               const float* __restrict__ kern, float* __restrict__ out)
{
    // Double-buffered W-sum planes: sw[par][ch][w][row]. 2*5*32*36*4 = 46080 B.
    __shared__ float sw[2][NCH][TW][PDIM];
    __shared__ float red[NT / 64];

    const int tid = threadIdx.x;
    const int w0 = blockIdx.x * TW;
    const int h0 = blockIdx.y * TH;
    const int b  = blockIdx.z / NDC;
    const int d0 = (blockIdx.z % NDC) * DCHUNK;
    const float k0 = kern[0];   // 1/125

    // ---- B-role: rows of W-sums from global (register sliding window) ----
    const bool isB = tid < (TH + 4) * 8;     // 288 threads: 36 rows x 8 w-quads
    const int g   = tid & 7;
    const int row = tid >> 3;                // 0..39 (valid < 36)
    const int gh  = h0 + row - 2;
    const bool hok = isB && gh >= 0 && gh < Hh;
    bool qok[3]; int qoff[3];
#pragma unroll
    for (int k = 0; k < 3; ++k) {
        int gw = w0 - 4 + 4 * (g + k);       // aligned quads, fully in or out
        qok[k]  = hok && gw >= 0 && gw <= Ww - 4;
        qoff[k] = gh * Ww + gw;
    }
    const size_t bb = (size_t)b * Dd * SLICE;
    const float* Mb = M + bb;
    const float* Rb = R + bb;

    float4 cm[2][3], cr[2][3];               // depth-2 prefetch (parity static)

    auto issue = [&](int s, int pp) {
        int dd = d0 - 2 + s;
        bool dok = dd >= 0 && dd < Dd;
        const float* Ms = Mb + (size_t)(dok ? dd : 0) * SLICE;
        const float* Rs = Rb + (size_t)(dok ? dd : 0) * SLICE;
#pragma unroll
        for (int k = 0; k < 3; ++k) {
            bool ok = dok && qok[k];
            cm[pp][k] = ok ? *(const float4*)(Ms + qoff[k]) : make_float4(0.f, 0.f, 0.f, 0.f);
            cr[pp][k] = ok ? *(const float4*)(Rs + qoff[k]) : make_float4(0.f, 0.f, 0.f, 0.f);
        }
    };

    auto bphase = [&](int sp) {
        if (!isB) return;
        float am[12], ar[12];
        *(float4*)&am[0] = cm[sp][0]; *(float4*)&am[4] = cm[sp][1]; *(float4*)&am[8] = cm[sp][2];
        *(float4*)&ar[0] = cr[sp][0]; *(float4*)&ar[4] = cr[sp][1]; *(float4*)&ar[8] = cr[sp][2];
        float mm[8], rr[8], mr[8];
#pragma unroll
        for (int k2 = 0; k2 < 8; ++k2) {
            float a = am[k2 + 2], r_ = ar[k2 + 2];
            mm[k2] = a * a; rr[k2] = r_ * r_; mr[k2] = a * r_;
        }
        float sm  = am[2] + am[3] + am[4] + am[5] + am[6];
        float sr_ = ar[2] + ar[3] + ar[4] + ar[5] + ar[6];
        float smm = mm[0] + mm[1] + mm[2] + mm[3] + mm[4];
        float srr = rr[0] + rr[1] + rr[2] + rr[3] + rr[4];
        float smr = mr[0] + mr[1] + mr[2] + mr[3] + mr[4];
#pragma unroll
        for (int j = 0; j < 4; ++j) {
            if (j) {
                sm  += am[j + 6] - am[j + 1];
                sr_ += ar[j + 6] - ar[j + 1];
                smm += mm[j + 4] - mm[j - 1];
                srr += rr[j + 4] - rr[j - 1];
                smr += mr[j + 4] - mr[j - 1];
            }
            const int wq = 4 * g + j;
            sw[sp][0][wq][row] = sm;
            sw[sp][1][wq][row] = sr_;
            sw[sp][2][wq][row] = smm;
            sw[sp][3][wq][row] = srr;
            sw[sp][4][wq][row] = smr;
        }
    };

    // ---- C-role: H-sums via b128 + running D-window ----
    const bool isC = tid < 256;
    const int cw = tid & 31;
    const int hg = (tid >> 5) & 7;

    float S[NCH][4];
    float ring[5][NCH][4];
#pragma unroll
    for (int c = 0; c < NCH; ++c)
#pragma unroll
        for (int j = 0; j < 4; ++j) {
            S[c][j] = 0.f;
#pragma unroll
            for (int t = 0; t < 5; ++t) ring[t][c][j] = 0.f;
        }
    float acc = 0.f;

    auto cphase = [&](int cs, int cp, int slot) {
        if (!isC) return;
        const float* base = &sw[cp][0][cw][hg * 4];
        float4 A  = *(const float4*)(base);
        float4 Bq = *(const float4*)(base + 4);
#pragma unroll
        for (int c = 0; c < NCH; ++c) {
            float4 An, Bn;
            if (c < 4) {
                An = *(const float4*)(base + (c + 1) * TW * PDIM);
                Bn = *(const float4*)(base + (c + 1) * TW * PDIM + 4);
            }
            float t0 = A.x + A.y + A.z + A.w + Bq.x;
            float t1 = t0 + Bq.y - A.x;
            float t2 = t1 + Bq.z - A.y;
            float t3 = t2 + Bq.w - A.z;
            S[c][0] += t0 - ring[slot][c][0]; ring[slot][c][0] = t0;
            S[c][1] += t1 - ring[slot][c][1]; ring[slot][c][1] = t1;
            S[c][2] += t2 - ring[slot][c][2]; ring[slot][c][2] = t2;
            S[c][3] += t3 - ring[slot][c][3]; ring[slot][c][3] = t3;
            A = An; Bq = Bn;
        }
        if (cs >= 4) {
#pragma unroll
            for (int j = 0; j < 4; ++j) {
                float Mm  = S[0][j] * k0, Rm = S[1][j] * k0;
                float MMm = S[2][j] * k0, RRm = S[3][j] * k0, MRm = S[4][j] * k0;
                float Mv = sqrtf(MMm - Mm * Mm + 1e-5f);
                float Rv = sqrtf(RRm - Rm * Rm + 1e-5f);
                acc += (MRm - Mm * Rm) / (Mv * Rv + 1e-5f);
            }
        }
    };

    // ---- prologue ----
    issue(0, 0);
    issue(1, 1);
    bphase(0);          // writes sw[0] for slice 0 (consumes pf[0])
    issue(2, 0);

    // ---- main loop: ONE barrier per slice; B(s) || C(s-1) on different buffers ----
    for (int m = 0; m < 2; ++m) {
#pragma unroll
        for (int k = 0; k < 10; ++k) {
            const int s  = m * 10 + k + 1;     // 1..20
            const int sp = (k + 1) & 1;        // s & 1 (static)
            const int cp = k & 1;              // (s-1) & 1 (static)
            const int sl = k % 5;              // (s-1) % 5 (static)
            bar_lgkm();
            if (s <= NSLICE - 1) {
                bphase(sp);
                if (s + 2 <= NSLICE - 1) issue(s + 2, sp);
            }
            cphase(s - 1, cp, sl);
        }
    }

    // ---- reduction -> one atomic ----
#pragma unroll
    for (int off = 32; off; off >>= 1) acc += __shfl_down(acc, off, 64);
    if ((tid & 63) == 0) red[tid >> 6] = acc;
    __syncthreads();
    if (tid == 0) {
        float t = red[0] + red[1] + red[2] + red[3] + red[4];
        atomicAdd(out, -t * (1.0f / 8192000.0f));   // mean over 2*160^3, negated
    }
}

extern "C" void kernel_launch(void* const* d_in, const int* in_sizes, int n_in,
                              void* d_out, int out_size, void* d_ws, size_t ws_size,
                              hipStream_t stream) {
    const float* M = (const float*)d_in[0];
    const float* R = (const float*)d_in[1];
    const float* K = (const float*)d_in[2];
    float* out = (float*)d_out;

    lncc_zero<<<1, 1, 0, stream>>>(out);

    dim3 grid(Ww / TW, Hh / TH, 2 * NDC);   // (5, 5, 20) = 500 blocks
    lncc_main<<<grid, NT, 0, stream>>>(M, R, K, out);
}